// Round 8
// baseline (1727.174 us; speedup 1.0000x reference)
//
#include <hip/hip_runtime.h>
#include <hip/hip_fp16.h>

typedef _Float16 v8h __attribute__((ext_vector_type(8)));
typedef _Float16 v4h __attribute__((ext_vector_type(4)));
typedef float v4f __attribute__((ext_vector_type(4)));

#define T_DIM 512
#define B_DIM 256
#define F_DIM 258
#define IN_DIM 256
#define H_DIM 1024
#define M_ROWS (T_DIM * B_DIM) /* 131072 */

// XCD-aware tile map: blocks on one XCD share an m-panel across all nt
__device__ __forceinline__ void tile_map(int b, int nM, int nN, int& mt, int& nt) {
    if ((nM & 7) == 0) {
        int xcd = b & 7;
        int l = b >> 3;
        int mpx = nM >> 3;
        int lm = l / nN;
        mt = xcd * mpx + lm;
        nt = l - lm * nN;
    } else {
        int lm = b / nN;
        mt = lm;
        nt = b - lm * nN;
    }
}

// async global->LDS, 16B per lane, lane-linear LDS destination
__device__ __forceinline__ void gl16(const _Float16* g, _Float16* l) {
    __builtin_amdgcn_global_load_lds(
        (const __attribute__((address_space(1))) unsigned int*)g,
        (__attribute__((address_space(3))) unsigned int*)l, 16, 0, 0);
}

// ---------------------------------------------------------------------------
// Activations in blocked "bk8" layout: X[m][k] at
//   ((m>>4)*(K>>3) + (k>>3))*128 + (m&15)*8 + (k&7)
// Weights fragment-major. All LDS reads are contiguous 1KB wave sweeps
// (zero bank conflicts); global_load_lds lane-linear dest maps 1:1.
// ---------------------------------------------------------------------------

// prep: u (Mc,258) fp32 -> X bk8 fp16, vectorized (v8h stores, linear in X)
__global__ void prep_x_kernel(const float* __restrict__ u,
                              _Float16* __restrict__ X, int nrows) {
    int i = blockIdx.x * blockDim.x + threadIdx.x;
    int total = nrows * 32;
    int stride = gridDim.x * blockDim.x;
    for (; i < total; i += stride) {
        int r = ((i >> 9) << 4) + (i & 15);
        int kb = (i >> 4) & 31;
        const float* s = u + (size_t)r * 258 + 2 + kb * 8;
        _Float16 h[8];
#pragma unroll
        for (int j = 0; j < 8; ++j) h[j] = (_Float16)s[j];
        *(v8h*)(X + ((size_t)(r >> 4) * 32 + kb) * 128 + (r & 15) * 8) =
            *(v8h*)h;
    }
}

__global__ void prep_c1_kernel(const float* __restrict__ u,
                               float* __restrict__ c1, int nrows) {
    int r = blockIdx.x * blockDim.x + threadIdx.x;
    if (r < nrows) c1[r] = u[(size_t)r * 258 + 1];
}

// weight -> fragment-major fp16. W (K x N fp32).
// Frag f=(g*KC+kc)*4+i holds n = g*64+i*16+(l&15), k = kc*32+(l>>4)*8+j.
__global__ void wt_frag_kernel(const float* __restrict__ W,
                               _Float16* __restrict__ BF, int K, int N) {
    int idx = blockIdx.x * blockDim.x + threadIdx.x;
    int total = (N >> 6) * (K >> 5) * 4 * 64;
    if (idx >= total) return;
    int l = idx & 63;
    int f = idx >> 6;
    int i = f & 3;
    int gk = f >> 2;
    int KC = K >> 5;
    int g = gk / KC, kc = gk - g * KC;
    int col = g * 64 + i * 16 + (l & 15);
    int krow = kc * 32 + (l >> 4) * 8;
    _Float16 tmp[8];
#pragma unroll
    for (int j = 0; j < 8; ++j) tmp[j] = (_Float16)W[(size_t)(krow + j) * N + col];
    *(v8h*)&BF[(size_t)idx * 8] = *(v8h*)tmp;
}

__global__ void wt_vec_kernel(const float* __restrict__ W,
                              _Float16* __restrict__ Wh, int K) {
    int i = blockIdx.x * blockDim.x + threadIdx.x;
    if (i < K) Wh[i] = (_Float16)W[i];
}

__global__ void zero_kernel(float* __restrict__ p, int n) {
    int i = blockIdx.x * blockDim.x + threadIdx.x;
    if (i < n) p[i] = 0.f;
}

// ---------------------------------------------------------------------------
// PERSISTENT 256x256 GEMM, 8 waves (2M x 4N), BK=32, TRIPLE-buffered 96KB
// LDS. Pipe-overlap structure (the R1-R7 invariant fix): step s issues
//   (a) 12 ds_reads of tile s+1 -> OTHER register set   (no MFMA dep!)
//   (b) 32 MFMAs of tile s from current register set
//   (c) epilogue on last K-step of an output tile
//   (d) 4 global_load_lds stages of tile s+3 -> buf[s%3]
//   (e) vmcnt(4) [confirm s+2, leave s+3 in flight] ; lgkmcnt(0) ; barrier
// DS port fills s+1's registers WHILE the MFMA pipe crunches s: the two
// pipes finally overlap instead of adding (the ~2x wall seen in R1-R7).
// Persistent grid (256 blocks, ~7 otiles each) keeps the pipeline flowing
// across output-tile switches and kills 14x per-block cold starts.
// ---------------------------------------------------------------------------
template <int DOT>
__global__ __launch_bounds__(512, 2)
void gemm_pers(const _Float16* __restrict__ Xb, const _Float16* __restrict__ WF,
               const float* __restrict__ bias, const _Float16* __restrict__ w3,
               _Float16* __restrict__ Cb, float* __restrict__ net,
               int M, int N, int K) {
    extern __shared__ _Float16 lds[];  // 3 bufs x (A 8192 | B 8192) elems
    const int tid = threadIdx.x;
    const int lane = tid & 63;
    const int wave = tid >> 6;
    const int wm = wave >> 2;  // 0..1 (128 m-rows each)
    const int wn = wave & 3;   // 0..3 (64 n-cols each)
    const int quad = lane >> 4;
    const int r16 = lane & 15;
    const int wm8 = wm * 8;
    const int lrb = lane * 8;

    const int nM = M >> 8, nN = N >> 8;
    const int nOT = nM * nN;
    const int KC = K >> 5;   // 32-k chunks = K-steps (BK=32)
    const int KC8 = K >> 3;
    const int NTk = KC;      // K-steps per output tile (8 or 32, even)
    const int gstride = gridDim.x;

    // 4 DMA ops per K-step tile: A 16KB (2 ops) + B 16KB (2 ops)
    auto stage = [&](int m016x, int nt4x, int ktx, _Float16* buf) {
#pragma unroll
        for (int op = 0; op < 2; ++op)
            gl16(WF + ((size_t)(nt4x + op * 2 + (tid >> 8)) * KC + ktx) * 2048 +
                     (tid & 255) * 8,
                 buf + op * 4096 + tid * 8);
#pragma unroll
        for (int op = 0; op < 2; ++op)
            gl16(Xb + ((size_t)(m016x + op * 8 + (tid >> 6)) * KC8 +
                       (size_t)ktx * 4) * 128 + (tid & 63) * 8,
                 buf + 8192 + op * 4096 + tid * 8);
    };

    v4f acc[8][4];
#pragma unroll
    for (int i = 0; i < 8; ++i)
#pragma unroll
        for (int j = 0; j < 4; ++j) acc[i][j] = (v4f)0.f;

    v8h afA[4], bfA[8], afB[4], bfB[8];
    int bi = 0;  // LDS buffer index of CURRENT compute tile

    int oi = blockIdx.x;
    if (oi >= nOT) return;

    // ---- prologue: stage first otile's tiles 0,1,2; read tile0 -> regsA ----
    {
        int mt0, nt0;
        tile_map(oi, nM, nN, mt0, nt0);
        int m016p = mt0 * 16, nt4p = nt0 * 4;
        stage(m016p, nt4p, 0, lds);
        stage(m016p, nt4p, 1, lds + 16384);
        stage(m016p, nt4p, 2, lds + 32768);
        asm volatile("s_waitcnt vmcnt(4)" ::: "memory");  // tiles 0,1 landed
        __builtin_amdgcn_s_barrier();
        _Float16* pA = lds;
        _Float16* pB = lds + 8192;
#pragma unroll
        for (int i = 0; i < 4; ++i)
            afA[i] = *(const v8h*)(pA + wn * 2048 + i * 512 + lrb);
#pragma unroll
        for (int mi = 0; mi < 8; ++mi)
            bfA[mi] = *(const v8h*)(pB + (wm8 + mi) * 512 + lrb);
        // all waves' tile-0 reads retired before anyone stages into buf0
        asm volatile("s_waitcnt lgkmcnt(0)" ::: "memory");
        __builtin_amdgcn_s_barrier();
    }

    for (; oi < nOT; oi += gstride) {
        int mt, nt;
        tile_map(oi, nM, nN, mt, nt);
        const int m016 = mt * 16, nt4 = nt * 4;
        const int m0 = mt * 256;
        const int nb = nt * 256 + wn * 64;
        const int oin = oi + gstride;
        const bool has_next = (oin < nOT);
        int m016n = 0, nt4n = 0;
        if (has_next) {
            int mtn, ntn;
            tile_map(oin, nM, nN, mtn, ntn);
            m016n = mtn * 16;
            nt4n = ntn * 4;
        }

        auto step = [&](int k, v8h (&caf)[4], v8h (&cbf)[8], v8h (&naf)[4],
                        v8h (&nbf)[8]) {
            int bi1 = bi + 1;
            if (bi1 == 3) bi1 = 0;
            const bool ep = (k == NTk - 1);
            // (a) read NEXT tile's operands (independent of this step's MFMA)
            if (!(ep && !has_next)) {
                _Float16* pA = lds + bi1 * 16384;
                _Float16* pB = pA + 8192;
#pragma unroll
                for (int i = 0; i < 4; ++i)
                    naf[i] = *(const v8h*)(pA + wn * 2048 + i * 512 + lrb);
#pragma unroll
                for (int mi = 0; mi < 8; ++mi)
                    nbf[mi] = *(const v8h*)(pB + (wm8 + mi) * 512 + lrb);
            }
            // (b) 32 MFMAs of current tile (registers ready since last step)
            __builtin_amdgcn_s_setprio(1);
#pragma unroll
            for (int mi = 0; mi < 8; ++mi)
#pragma unroll
                for (int ni = 0; ni < 4; ++ni)
                    acc[mi][ni] = __builtin_amdgcn_mfma_f32_16x16x32_f16(
                        caf[ni], cbf[mi], acc[mi][ni], 0, 0, 0);
            __builtin_amdgcn_s_setprio(0);
            // (c) epilogue on last K-step of this output tile
            if (ep) {
                v4f bv[4];
#pragma unroll
                for (int ni = 0; ni < 4; ++ni)
                    bv[ni] = *(const v4f*)&bias[nb + ni * 16 + quad * 4];
                if constexpr (DOT == 0) {
                    const int NC8 = N >> 3;
#pragma unroll
                    for (int ni = 0; ni < 4; ++ni) {
                        const int nblk = ((nb + ni * 16) >> 3) + (quad >> 1);
#pragma unroll
                        for (int mi = 0; mi < 8; ++mi) {
                            v4h hv;
#pragma unroll
                            for (int i = 0; i < 4; ++i)
                                hv[i] = (_Float16)fmaxf(
                                    acc[mi][ni][i] + bv[ni][i], 0.f);
                            const size_t mblk =
                                (size_t)((m0 + wm * 128 + mi * 16) >> 4);
                            *(v4h*)(Cb + (mblk * NC8 + nblk) * 128 + r16 * 8 +
                                    (quad & 1) * 4) = hv;
                        }
                    }
                } else {
                    v4h wv[4];
#pragma unroll
                    for (int ni = 0; ni < 4; ++ni)
                        wv[ni] = *(const v4h*)&w3[nb + ni * 16 + quad * 4];
#pragma unroll
                    for (int mi = 0; mi < 8; ++mi) {
                        float t = 0.f;
#pragma unroll
                        for (int ni = 0; ni < 4; ++ni)
#pragma unroll
                            for (int i = 0; i < 4; ++i) {
                                float v =
                                    fmaxf(acc[mi][ni][i] + bv[ni][i], 0.f);
                                t = fmaf(v, (float)wv[ni][i], t);
                            }
                        t += __shfl_xor(t, 16);
                        t += __shfl_xor(t, 32);
                        if (quad == 0) {
                            int row = m0 + wm * 128 + mi * 16 + r16;
                            atomicAdd(&net[row], t);
                        }
                    }
                }
#pragma unroll
                for (int i = 0; i < 8; ++i)
#pragma unroll
                    for (int j = 0; j < 4; ++j) acc[i][j] = (v4f)0.f;
            }
            // (d) stage tile s+3 into this tile's buffer (reads of it retired
            //     one step ago, enforced by the lgkmcnt(0)+barrier below)
            bool staged = true;
            if (k + 3 < NTk)
                stage(m016, nt4, k + 3, lds + bi * 16384);
            else if (has_next)
                stage(m016n, nt4n, k + 3 - NTk, lds + bi * 16384);
            else
                staged = false;
            // (e) boundary: confirm s+2 (counted, s+3 stays in flight)
            if (!(ep && !has_next)) {
                if (staged)
                    asm volatile("s_waitcnt vmcnt(4)" ::: "memory");
                else
                    asm volatile("s_waitcnt vmcnt(0)" ::: "memory");
                asm volatile("s_waitcnt lgkmcnt(0)" ::: "memory");
                __builtin_amdgcn_s_barrier();
            }
            bi = bi1;
        };

        for (int k = 0; k < NTk; k += 2) {
            step(k, afA, bfA, afB, bfB);
            step(k + 1, afB, bfB, afA, bfA);
        }
    }
}

// ---------------------------------------------------------------------------
// scan: y_t = a*y_{t-1} + b*c1_t + (net_t + b3) ; out = [y0; ys]
// ---------------------------------------------------------------------------
__global__ void scan_kernel(const float* __restrict__ net,
                            const float* __restrict__ c1,
                            const float* __restrict__ u,
                            const float* __restrict__ pa,
                            const float* __restrict__ pb,
                            const float* __restrict__ pb3,
                            float* __restrict__ out) {
    const int bidx = threadIdx.x;  // 0..255
    const float a = pa[0];
    const float b = pb[0];
    const float b3 = pb3[0];
    float y = u[(size_t)bidx * F_DIM];  // u[0, b, 0]
    out[bidx] = y;
#pragma unroll 8
    for (int t = 0; t < T_DIM; ++t) {
        float z = fmaf(b, c1[t * B_DIM + bidx], net[t * B_DIM + bidx] + b3);
        y = fmaf(a, y, z);
        out[(t + 1) * B_DIM + bidx] = y;
    }
}

// ---------------------------------------------------------------------------
extern "C" void kernel_launch(void* const* d_in, const int* in_sizes, int n_in,
                              void* d_out, int out_size, void* d_ws, size_t ws_size,
                              hipStream_t stream) {
    const float* u = (const float*)d_in[0];
    const float* pa = (const float*)d_in[1];
    const float* pb = (const float*)d_in[2];
    const float* W0 = (const float*)d_in[3];
    const float* b0 = (const float*)d_in[4];
    const float* W1 = (const float*)d_in[5];
    const float* b1 = (const float*)d_in[6];
    const float* W2 = (const float*)d_in[7];
    const float* b2 = (const float*)d_in[8];
    const float* W3 = (const float*)d_in[9];
    const float* b3 = (const float*)d_in[10];
    float* out = (float*)d_out;

    char* ws = (char*)d_ws;
    size_t off = 0;
    auto alloc = [&](size_t bytes) -> void* {
        void* p = ws + off;
        off += (bytes + 255) & ~(size_t)255;
        return p;
    };

    // ---- fixed residents (~5.8 MB) ----
    float* net = (float*)alloc((size_t)M_ROWS * 4);
    float* c1 = (float*)alloc((size_t)M_ROWS * 4);
    _Float16* W0F = (_Float16*)alloc((size_t)IN_DIM * H_DIM * 2);
    _Float16* W1F = (_Float16*)alloc((size_t)H_DIM * H_DIM * 2);
    _Float16* W2F = (_Float16*)alloc((size_t)H_DIM * H_DIM * 2);
    _Float16* W3h = (_Float16*)alloc((size_t)H_DIM * 2);

    // ---- chunk rows: multiple of 2048 ----
    const size_t per_row = 512 + 2048 + 2048;
    size_t avail = (ws_size > off + 65536) ? (ws_size - off - 65536) : 0;
    long Rl = (long)(avail / per_row);
    Rl = (Rl / 2048) * 2048;
    if (Rl < 2048) Rl = 2048;
    if (Rl > M_ROWS) Rl = M_ROWS;
    const int R = (int)Rl;

    _Float16* Xc = (_Float16*)alloc((size_t)R * IN_DIM * 2);
    _Float16* HAc = (_Float16*)alloc((size_t)R * H_DIM * 2);
    _Float16* HBc = (_Float16*)alloc((size_t)R * H_DIM * 2);

    // ---- weights once per call (fragment-major) ----
    wt_frag_kernel<<<(IN_DIM / 32) * (H_DIM / 64), 256, 0, stream>>>(W0, W0F,
                                                                     IN_DIM, H_DIM);
    wt_frag_kernel<<<(H_DIM / 32) * (H_DIM / 64), 256, 0, stream>>>(W1, W1F,
                                                                    H_DIM, H_DIM);
    wt_frag_kernel<<<(H_DIM / 32) * (H_DIM / 64), 256, 0, stream>>>(W2, W2F,
                                                                    H_DIM, H_DIM);
    wt_vec_kernel<<<4, 256, 0, stream>>>(W3, W3h, H_DIM);
    zero_kernel<<<M_ROWS / 256, 256, 0, stream>>>(net, M_ROWS);

    // ---- chunked MLP pipeline ----
    const size_t lds_bytes = 98304;  // 3 x (A 16KB + B 16KB)
    for (int r0 = 0; r0 < M_ROWS; r0 += R) {
        int Mc = M_ROWS - r0;
        if (Mc > R) Mc = R;

        int pgrid = (Mc * 32 + 255) / 256;
        if (pgrid > 2048) pgrid = 2048;
        prep_x_kernel<<<pgrid, 256, 0, stream>>>(u + (size_t)r0 * F_DIM, Xc, Mc);
        prep_c1_kernel<<<(Mc + 255) / 256, 256, 0, stream>>>(
            u + (size_t)r0 * F_DIM, c1 + r0, Mc);

        int nOT = (Mc >> 8) * (H_DIM >> 8);
        int g = nOT < 256 ? nOT : 256;
        dim3 blk(512);
        gemm_pers<0><<<g, blk, lds_bytes, stream>>>(Xc, W0F, b0, nullptr, HAc,
                                                    nullptr, Mc, H_DIM, IN_DIM);
        gemm_pers<0><<<g, blk, lds_bytes, stream>>>(HAc, W1F, b1, nullptr, HBc,
                                                    nullptr, Mc, H_DIM, H_DIM);
        gemm_pers<1><<<g, blk, lds_bytes, stream>>>(HBc, W2F, b2, W3h, nullptr,
                                                    net + r0, Mc, H_DIM, H_DIM);
    }

    // ---- scan ----
    scan_kernel<<<1, 256, 0, stream>>>(net, c1, u, pa, pb, b3, out);
}